// Round 1
// baseline (1403.051 us; speedup 1.0000x reference)
//
#include <hip/hip_runtime.h>
#include <hip/hip_bf16.h>
#include <math.h>

typedef __bf16 bf16_t;
typedef float floatx4 __attribute__((ext_vector_type(4)));
typedef bf16_t bf16x8 __attribute__((ext_vector_type(8)));

typedef __attribute__((address_space(1))) void g_void;
typedef __attribute__((address_space(3))) void lds_void;

__device__ __forceinline__ void ldg_lds16(const bf16_t* g, bf16_t* l) {
    __builtin_amdgcn_global_load_lds((g_void*)g, (lds_void*)l, 16, 0, 0);
}

__device__ __forceinline__ void unpack8(uint4 r, float* o) {
    o[0] = __uint_as_float((r.x & 0xffffu) << 16); o[1] = __uint_as_float(r.x & 0xffff0000u);
    o[2] = __uint_as_float((r.y & 0xffffu) << 16); o[3] = __uint_as_float(r.y & 0xffff0000u);
    o[4] = __uint_as_float((r.z & 0xffffu) << 16); o[5] = __uint_as_float(r.z & 0xffff0000u);
    o[6] = __uint_as_float((r.w & 0xffffu) << 16); o[7] = __uint_as_float(r.w & 0xffff0000u);
}
__device__ __forceinline__ void unpack4(uint2 r, float* o) {
    o[0] = __uint_as_float((r.x & 0xffffu) << 16); o[1] = __uint_as_float(r.x & 0xffff0000u);
    o[2] = __uint_as_float((r.y & 0xffffu) << 16); o[3] = __uint_as_float(r.y & 0xffff0000u);
}

// ---------------- weight fp32 -> bf16 conversion (re-done each call; ws re-poisoned) ----
__global__ void cvt_weights(const float* __restrict__ sqkvw, const float* __restrict__ sow,
                            const float* __restrict__ sl1w,  const float* __restrict__ sl2w,
                            const float* __restrict__ tqkvw, const float* __restrict__ tow,
                            const float* __restrict__ tl1w,  const float* __restrict__ tl2w,
                            bf16_t* __restrict__ dst) {
    int i = blockIdx.x * 256 + threadIdx.x;  // total 1310720
    float v;
    if      (i <  393216) v = sqkvw[i];
    else if (i <  524288) v = sow  [i -  393216];
    else if (i <  589824) v = sl1w [i -  524288];
    else if (i <  655360) v = sl2w [i -  589824];
    else if (i < 1048576) v = tqkvw[i -  655360];
    else if (i < 1179648) v = tow  [i - 1048576];
    else if (i < 1245184) v = tl1w [i - 1179648];
    else                  v = tl2w [i - 1245184];
    dst[i] = (bf16_t)v;
}

// ---------------- embed: gelu(moveinfo @ w_in^T + b_in), cls=1e-5, layout [BC,9,256] ----
__global__ void embed_k(const float* __restrict__ mv, const float* __restrict__ w_in,
                        const float* __restrict__ b_in, bf16_t* __restrict__ x, int b0) {
    int blk = blockIdx.x; int d = threadIdx.x;
    int tok = blk % 9; int lb = blk / 9;
    size_t oidx = (size_t)blk * 256 + d;
    if (tok == 0) { x[oidx] = (bf16_t)1e-5f; return; }
    int bb = b0 + lb; int t = bb >> 8; int s = bb & 255;   // b = t*256+s
    int n = s * 8 + (tok - 1);
    float m0 = mv[((size_t)n * 64 + t) * 2];
    float m1 = mv[((size_t)n * 64 + t) * 2 + 1];
    float v = m0 * w_in[2 * d] + m1 * w_in[2 * d + 1] + b_in[d];
    v = 0.5f * v * (1.0f + erff(v * 0.70710678118654752f));  // exact gelu
    x[oidx] = (bf16_t)v;
}

// ---------------- cls extract: t_x[s*64+t, :] = x[lb, 0, :] -------------------------------
__global__ void cls_k(const bf16_t* __restrict__ x, bf16_t* __restrict__ tx, int b0) {
    int lb = blockIdx.x; int d = threadIdx.x;
    int bb = b0 + lb; int t = bb >> 8; int s = bb & 255;
    tx[((size_t)(s * 64 + t)) * 256 + d] = x[(size_t)lb * 2304 + d];
}

// ---------------- GEMM: C[M,N] = A[M,K] @ W[N,K]^T + bias, optional relu, bf16 out --------
// 128x128 tile, 4 waves (2x2 of 64x64), mfma_f32_16x16x32_bf16, global_load_lds width 16.
__global__ __launch_bounds__(256) void gemm_bt(const bf16_t* __restrict__ A,
                                               const bf16_t* __restrict__ W,
                                               const float* __restrict__ bias,
                                               bf16_t* __restrict__ C,
                                               int M, int N, int K, int relu) {
    __shared__ __align__(16) bf16_t As[4096];  // [128][32]
    __shared__ __align__(16) bf16_t Ws[4096];  // [128][32]
    int tid = threadIdx.x;
    int lane = tid & 63;
    int wave = tid >> 6;
    int m0 = blockIdx.x * 128;
    int n0 = blockIdx.y * 128;
    int wm = (wave & 1) * 64;
    int wn = (wave >> 1) * 64;
    int arow = tid >> 2;          // 0..63
    int acol = (tid & 3) * 8;     // 0,8,16,24
    int fm = lane & 15;
    int fq = lane >> 4;

    floatx4 acc[4][4] = {};

    const bf16_t* Ag = A + (size_t)(m0 + arow) * K + acol;
    const bf16_t* Wg = W + (size_t)(n0 + arow) * K + acol;

    for (int k0 = 0; k0 < K; k0 += 32) {
        __syncthreads();
        ldg_lds16(Ag + k0,                     &As[tid * 8]);
        ldg_lds16(Ag + k0 + (size_t)64 * K,    &As[2048 + tid * 8]);
        ldg_lds16(Wg + k0,                     &Ws[tid * 8]);
        ldg_lds16(Wg + k0 + (size_t)64 * K,    &Ws[2048 + tid * 8]);
        __syncthreads();  // compiler drains vmcnt before s_barrier

        bf16x8 af[4], wf[4];
#pragma unroll
        for (int mi = 0; mi < 4; mi++)
            af[mi] = *(const bf16x8*)&As[(wm + mi * 16 + fm) * 32 + fq * 8];
#pragma unroll
        for (int ni = 0; ni < 4; ni++)
            wf[ni] = *(const bf16x8*)&Ws[(wn + ni * 16 + fm) * 32 + fq * 8];
#pragma unroll
        for (int mi = 0; mi < 4; mi++)
#pragma unroll
            for (int ni = 0; ni < 4; ni++)
                acc[mi][ni] = __builtin_amdgcn_mfma_f32_16x16x32_bf16(af[mi], wf[ni], acc[mi][ni], 0, 0, 0);
    }

#pragma unroll
    for (int mi = 0; mi < 4; mi++) {
#pragma unroll
        for (int ni = 0; ni < 4; ni++) {
            int col = n0 + wn + ni * 16 + fm;      // D col = lane&15 (B-side n)
            float bcol = bias[col];
#pragma unroll
            for (int r = 0; r < 4; r++) {
                int row = m0 + wm + mi * 16 + fq * 4 + r;  // D row = quad*4+reg (A-side m)
                float v = acc[mi][ni][r] + bcol;
                if (relu) v = fmaxf(v, 0.f);
                C[(size_t)row * N + col] = (bf16_t)v;
            }
        }
    }
}

// ---------------- attention, seqlen 9 (stage B): one block per sequence -------------------
__global__ __launch_bounds__(128) void attn9_k(const bf16_t* __restrict__ qkv,
                                               bf16_t* __restrict__ ao) {
    __shared__ float sb[6912];  // [9][768] fp32
    int b = blockIdx.x; int tid = threadIdx.x;
    const bf16_t* src = qkv + (size_t)b * 6912;
    for (int c = tid; c < 864; c += 128) {
        uint4 r = *(const uint4*)(src + c * 8);
        float o[8]; unpack8(r, o);
#pragma unroll
        for (int j = 0; j < 8; j++) sb[c * 8 + j] = o[j];
    }
    __syncthreads();
    if (tid < 72) {
        int h = tid / 9, i = tid % 9;
        const float* qr = sb + i * 768 + h * 32;
        float sc[9]; float mx = -1e30f;
#pragma unroll
        for (int j = 0; j < 9; j++) {
            const float* kr = sb + j * 768 + 256 + h * 32;
            float d = 0.f;
#pragma unroll
            for (int dd = 0; dd < 32; dd++) d += qr[dd] * kr[dd];
            d *= 0.17677669529663687f;  // 1/sqrt(32)
            sc[j] = d; mx = fmaxf(mx, d);
        }
        float den = 0.f;
#pragma unroll
        for (int j = 0; j < 9; j++) { sc[j] = __expf(sc[j] - mx); den += sc[j]; }
        float inv = 1.0f / den;
        bf16_t* dst = ao + (size_t)b * 2304 + i * 256 + h * 32;
#pragma unroll
        for (int dd = 0; dd < 32; dd++) {
            float o = 0.f;
#pragma unroll
            for (int j = 0; j < 9; j++) o += sc[j] * sb[j * 768 + 512 + h * 32 + dd];
            dst[dd] = (bf16_t)(o * inv);
        }
    }
}

// ---------------- attention, seqlen 64 (stage C): one wave per (seq, head) ----------------
__global__ __launch_bounds__(64) void attn64_k(const bf16_t* __restrict__ qkv,
                                               bf16_t* __restrict__ ao) {
    __shared__ float kk[64][32];
    __shared__ float vv[64][32];
    int s = blockIdx.x >> 3, h = blockIdx.x & 7;
    int i = threadIdx.x;  // token row loaded AND query index
    const bf16_t* base = qkv + ((size_t)(s * 64 + i)) * 768 + h * 32;
    float qf[32];
#pragma unroll
    for (int c = 0; c < 4; c++) { uint4 r = *(const uint4*)(base + c * 8); unpack8(r, qf + c * 8); }
#pragma unroll
    for (int c = 0; c < 4; c++) {
        uint4 r = *(const uint4*)(base + 256 + c * 8);
        float tmp[8]; unpack8(r, tmp);
#pragma unroll
        for (int j = 0; j < 8; j++) kk[i][c * 8 + j] = tmp[j];
    }
#pragma unroll
    for (int c = 0; c < 4; c++) {
        uint4 r = *(const uint4*)(base + 512 + c * 8);
        float tmp[8]; unpack8(r, tmp);
#pragma unroll
        for (int j = 0; j < 8; j++) vv[i][c * 8 + j] = tmp[j];
    }
    __syncthreads();
    float sc[64]; float mx = -1e30f;
#pragma unroll
    for (int j = 0; j < 64; j++) {
        float d = 0.f;
#pragma unroll
        for (int dd = 0; dd < 32; dd++) d += qf[dd] * kk[j][dd];
        d *= 0.17677669529663687f;
        sc[j] = d; mx = fmaxf(mx, d);
    }
    float den = 0.f;
#pragma unroll
    for (int j = 0; j < 64; j++) { sc[j] = __expf(sc[j] - mx); den += sc[j]; }
    float inv = 1.0f / den;
    bf16_t* dst = ao + ((size_t)(s * 64 + i)) * 256 + h * 32;
#pragma unroll
    for (int dd = 0; dd < 32; dd++) {
        float o = 0.f;
#pragma unroll
        for (int j = 0; j < 64; j++) o += sc[j] * vv[j][dd];
        dst[dd] = (bf16_t)(o * inv);
    }
}

// ---------------- residual + LayerNorm: out = LN(xin+add)*w+b; one wave per 256-dim row ---
__global__ __launch_bounds__(256) void resln_k(const bf16_t* __restrict__ xin,
                                               const bf16_t* __restrict__ add,
                                               const float* __restrict__ w,
                                               const float* __restrict__ b,
                                               bf16_t* out_bf, float* out_f) {
    int row = blockIdx.x * 4 + (threadIdx.x >> 6);
    int lane = threadIdx.x & 63;
    size_t base = (size_t)row * 256 + lane * 4;
    float xv[4], av[4], v[4];
    unpack4(*(const uint2*)(xin + base), xv);
    unpack4(*(const uint2*)(add + base), av);
    float s = 0.f, ss = 0.f;
#pragma unroll
    for (int i = 0; i < 4; i++) { v[i] = xv[i] + av[i]; s += v[i]; ss += v[i] * v[i]; }
#pragma unroll
    for (int off = 32; off > 0; off >>= 1) {
        s += __shfl_xor(s, off, 64);
        ss += __shfl_xor(ss, off, 64);
    }
    float mean = s * (1.f / 256.f);
    float var = ss * (1.f / 256.f) - mean * mean;
    float inv = rsqrtf(var + 1e-5f);
#pragma unroll
    for (int i = 0; i < 4; i++) {
        float o = (v[i] - mean) * inv * w[lane * 4 + i] + b[lane * 4 + i];
        if (out_f) out_f[base + i] = o;
        else       out_bf[base + i] = (bf16_t)o;
    }
}

// ------------------------------------------------------------------------------------------
extern "C" void kernel_launch(void* const* d_in, const int* in_sizes, int n_in,
                              void* d_out, int out_size, void* d_ws, size_t ws_size,
                              hipStream_t stream) {
    const float* mv   = (const float*)d_in[0];
    // d_in[1] = seq_start_end: setup guarantees starts = arange(S)*L -> implicit layout
    const float* w_in = (const float*)d_in[2];
    const float* b_in = (const float*)d_in[3];
    const float* sp[12]; const float* tp[12];
    for (int i = 0; i < 12; i++) { sp[i] = (const float*)d_in[4 + i]; tp[i] = (const float*)d_in[16 + i]; }
    // idx: 0 qkvw, 1 qkvb, 2 ow, 3 ob, 4 l1w, 5 l1b, 6 l2w, 7 l2b, 8 ln1w, 9 ln1b, 10 ln2w, 11 ln2b

    bf16_t* wbf  = (bf16_t*)d_ws;             // 1310720 elems of bf16 weights
    bf16_t* txb  = wbf + 1310720;             // t_x: 16384*256
    bf16_t* pool = txb + 4194304;             // chunk pool / stage-C pool

    // choose chunk size BC (sequences) to fit workspace
    long long cand[5] = {16384, 8192, 4096, 2048, 1024};
    int BC = 1024;
    for (int c = 0; c < 5; c++) {
        long long poolel = cand[c] * 11520;                    // x(2304)+qkv(6912)+ao(2304) per seq
        if (poolel < 16777216LL) poolel = 16777216LL;          // stage-C floor
        long long need = 2LL * (1310720 + 4194304 + poolel);
        if ((size_t)need <= ws_size) { BC = (int)cand[c]; break; }
    }

    cvt_weights<<<5120, 256, 0, stream>>>(sp[0], sp[2], sp[4], sp[6], tp[0], tp[2], tp[4], tp[6], wbf);

    const int M = BC * 9;
    bf16_t* xc   = pool;
    bf16_t* qkvb_ = pool + (long long)BC * 2304;
    bf16_t* aob  = qkvb_ + (long long)BC * 6912;
    bf16_t* hb   = qkvb_ + (long long)M * 256;   // h inside qkv region (after pb consumed)

    for (int b0 = 0; b0 < 16384; b0 += BC) {
        embed_k<<<dim3(M), 256, 0, stream>>>(mv, w_in, b_in, xc, b0);
        for (int l = 0; l < 2; l++) {
            const bf16_t* wq = wbf + 0      + l * 196608;
            const bf16_t* wo = wbf + 393216 + l * 65536;
            const bf16_t* w1 = wbf + 524288 + l * 32768;
            const bf16_t* w2 = wbf + 589824 + l * 32768;
            gemm_bt<<<dim3(M / 128, 6), 256, 0, stream>>>(xc, wq, sp[1] + l * 768, qkvb_, M, 768, 256, 0);
            attn9_k<<<dim3(BC), 128, 0, stream>>>(qkvb_, aob);
            gemm_bt<<<dim3(M / 128, 2), 256, 0, stream>>>(aob, wo, sp[3] + l * 256, qkvb_, M, 256, 256, 0);
            resln_k<<<dim3(M / 4), 256, 0, stream>>>(xc, qkvb_, sp[8] + l * 256, sp[9] + l * 256, xc, (float*)nullptr);
            gemm_bt<<<dim3(M / 128, 1), 256, 0, stream>>>(xc, w1, sp[5] + l * 128, hb, M, 128, 256, 1);
            gemm_bt<<<dim3(M / 128, 2), 256, 0, stream>>>(hb, w2, sp[7] + l * 256, qkvb_, M, 256, 128, 0);
            resln_k<<<dim3(M / 4), 256, 0, stream>>>(xc, qkvb_, sp[10] + l * 256, sp[11] + l * 256, xc, (float*)nullptr);
        }
        cls_k<<<dim3(BC), 256, 0, stream>>>(xc, txb, b0);
    }

    // ---- stage C: 256 seqs x 64 tokens over t_x [16384, 256] ----
    const int Mt = 16384;
    bf16_t* tqkv = pool;                  // 16384*768
    bf16_t* tao  = pool + 12582912;       // 16384*256
    bf16_t* th   = pool + 4194304;        // 16384*128, after pb region
    for (int l = 0; l < 2; l++) {
        gemm_bt<<<dim3(128, 6), 256, 0, stream>>>(txb, wbf + 655360 + l * 196608, tp[1] + l * 768, tqkv, Mt, 768, 256, 0);
        attn64_k<<<dim3(2048), 64, 0, stream>>>(tqkv, tao);
        gemm_bt<<<dim3(128, 2), 256, 0, stream>>>(tao, wbf + 1048576 + l * 65536, tp[3] + l * 256, pool, Mt, 256, 256, 0);
        resln_k<<<dim3(4096), 256, 0, stream>>>(txb, pool, tp[8] + l * 256, tp[9] + l * 256, txb, (float*)nullptr);
        gemm_bt<<<dim3(128, 1), 256, 0, stream>>>(txb, wbf + 1179648 + l * 32768, tp[5] + l * 128, th, Mt, 128, 256, 1);
        gemm_bt<<<dim3(128, 2), 256, 0, stream>>>(th, wbf + 1245184 + l * 32768, tp[7] + l * 256, pool, Mt, 256, 128, 0);
        if (l == 0)
            resln_k<<<dim3(4096), 256, 0, stream>>>(txb, pool, tp[10] + l * 256, tp[11] + l * 256, txb, (float*)nullptr);
        else
            resln_k<<<dim3(4096), 256, 0, stream>>>(txb, pool, tp[10] + l * 256, tp[11] + l * 256, (bf16_t*)nullptr, (float*)d_out);
    }
}